// Round 3
// baseline (443.756 us; speedup 1.0000x reference)
//
#include <hip/hip_runtime.h>

// QuantizationLayer: x in [0,1) -> n = round_half_even(x * 2^B - 0.5) in [0, 2^B)
// -> emit B bits MSB-first as float32 (0.0 / 1.0).
//
// B == 4 fast path: each input element -> one aligned float4 of output.
// Vectorized: each thread loads one float4 (4 elems), writes 64 B contiguous
// (4x global_store_dwordx4, nontemporal). Exact-size grid, no loop.

typedef __attribute__((ext_vector_type(4))) float f32x4;

__global__ __launch_bounds__(256) void quant_bits4_vec(
    const f32x4* __restrict__ x4, f32x4* __restrict__ out4, int n4) {
    int i = blockIdx.x * blockDim.x + threadIdx.x;
    if (i >= n4) return;
    f32x4 v = __builtin_nontemporal_load(&x4[i]);
#pragma unroll
    for (int k = 0; k < 4; ++k) {
        // x*16 exact (pow2 scale); v_rndne_f32 == np.round (half-to-even);
        // rintf(-0.5) = -0.0 -> (int)0 matches uint8 cast of np.round.
        int n = (int)rintf(v[k] * 16.0f - 0.5f);
        f32x4 o;
        o.x = (float)((n >> 3) & 1);
        o.y = (float)((n >> 2) & 1);
        o.z = (float)((n >> 1) & 1);
        o.w = (float)(n & 1);
        __builtin_nontemporal_store(o, &out4[i * 4 + k]);
    }
}

// Scalar tail / odd-n fallback (B == 4)
__global__ __launch_bounds__(256) void quant_bits4_scalar(
    const float* __restrict__ x, float* __restrict__ out, int n_elems, int start) {
    int i = start + blockIdx.x * blockDim.x + threadIdx.x;
    if (i >= n_elems) return;
    int n = (int)rintf(x[i] * 16.0f - 0.5f);
    f32x4 o;
    o.x = (float)((n >> 3) & 1);
    o.y = (float)((n >> 2) & 1);
    o.z = (float)((n >> 1) & 1);
    o.w = (float)(n & 1);
    __builtin_nontemporal_store(o, (f32x4*)&out[(long long)i * 4]);
}

// Generic fallback for any B (1..8)
__global__ __launch_bounds__(256) void quant_bits_generic_kernel(
    const float* __restrict__ x, float* __restrict__ out, int n_elems, int B) {
    int idx = blockIdx.x * blockDim.x + threadIdx.x;
    int stride = gridDim.x * blockDim.x;
    float step = (float)(1 << B);
    for (int i = idx; i < n_elems; i += stride) {
        float v = x[i];
        int n = (int)rintf(v * step - 0.5f);
        for (int j = 0; j < B; ++j) {
            out[(long long)i * B + j] = (float)((n >> (B - 1 - j)) & 1);
        }
    }
}

extern "C" void kernel_launch(void* const* d_in, const int* in_sizes, int n_in,
                              void* d_out, int out_size, void* d_ws, size_t ws_size,
                              hipStream_t stream) {
    const float* x = (const float*)d_in[0];
    float* out = (float*)d_out;
    int n = in_sizes[0];
    int B = out_size / n;  // bits per element, known on host

    const int threads = 256;

    if (B == 4) {
        int n4 = n >> 2;  // float4-covered elements
        if (n4 > 0) {
            int blocks = (n4 + threads - 1) / threads;
            quant_bits4_vec<<<blocks, threads, 0, stream>>>(
                (const f32x4*)x, (f32x4*)out, n4);
        }
        int tail = n - (n4 << 2);
        if (tail > 0) {
            quant_bits4_scalar<<<1, 64, 0, stream>>>(x, out, n, n4 << 2);
        }
    } else {
        int blocks = (n + threads - 1) / threads;
        if (blocks > 2048) blocks = 2048;
        quant_bits_generic_kernel<<<blocks, threads, 0, stream>>>(x, out, n, B);
    }
}

// Round 6
// 320.696 us; speedup vs baseline: 1.3837x; 1.3837x over previous
//
#include <hip/hip_runtime.h>

// QuantizationLayer: x in [0,1) -> n = round_half_even(x * 2^B - 0.5) in [0, 2^B)
// -> emit B bits MSB-first as float32 (0.0 / 1.0).
//
// B == 4: each input element -> one aligned float4 of output (16 B).
// Layout lesson (round 3): stores MUST be lane-contiguous per instruction.
// Thread t handles elements {t, t+C, t+2C, t+3C}, C = n/4: every load is
// 4 B/lane coalesced, every store is 16 B/lane with consecutive lanes ->
// 1 KB contiguous per wave per store instruction. ILP = 4, fully unrolled.
// Plain (cached) loads/stores: L3 absorbs part of the read stream; NT partial
// lines caused 2x WRITE_SIZE in round 3.

typedef __attribute__((ext_vector_type(4))) float f32x4;

__global__ __launch_bounds__(256) void quant_b4_chunk(
    const float* __restrict__ x, f32x4* __restrict__ out4, int chunk) {
    int t = blockIdx.x * blockDim.x + threadIdx.x;
    if (t >= chunk) return;
#pragma unroll
    for (int k = 0; k < 4; ++k) {
        int e = t + k * chunk;
        // x*16 exact (pow2 scale); v_rndne_f32 == np.round (half-to-even);
        // rintf(-0.5) = -0.0 -> (int)0 matches uint8 cast of np.round.
        int n = (int)rintf(x[e] * 16.0f - 0.5f);
        f32x4 o;
        o.x = (float)((n >> 3) & 1);
        o.y = (float)((n >> 2) & 1);
        o.z = (float)((n >> 1) & 1);
        o.w = (float)(n & 1);
        out4[e] = o;
    }
}

// Tail for n not divisible by 4 (elements [start, n))
__global__ __launch_bounds__(256) void quant_b4_tail(
    const float* __restrict__ x, f32x4* __restrict__ out4, int n_elems, int start) {
    int i = start + blockIdx.x * blockDim.x + threadIdx.x;
    if (i >= n_elems) return;
    int n = (int)rintf(x[i] * 16.0f - 0.5f);
    f32x4 o;
    o.x = (float)((n >> 3) & 1);
    o.y = (float)((n >> 2) & 1);
    o.z = (float)((n >> 1) & 1);
    o.w = (float)(n & 1);
    out4[i] = o;
}

// Generic fallback for any B (1..8)
__global__ __launch_bounds__(256) void quant_bits_generic_kernel(
    const float* __restrict__ x, float* __restrict__ out, int n_elems, int B) {
    int idx = blockIdx.x * blockDim.x + threadIdx.x;
    int stride = gridDim.x * blockDim.x;
    float step = (float)(1 << B);
    for (int i = idx; i < n_elems; i += stride) {
        float v = x[i];
        int n = (int)rintf(v * step - 0.5f);
        for (int j = 0; j < B; ++j) {
            out[(long long)i * B + j] = (float)((n >> (B - 1 - j)) & 1);
        }
    }
}

extern "C" void kernel_launch(void* const* d_in, const int* in_sizes, int n_in,
                              void* d_out, int out_size, void* d_ws, size_t ws_size,
                              hipStream_t stream) {
    const float* x = (const float*)d_in[0];
    float* out = (float*)d_out;
    int n = in_sizes[0];
    int B = out_size / n;  // bits per element, known on host

    const int threads = 256;

    if (B == 4) {
        int chunk = n >> 2;  // elements per stream; 4 streams per thread
        if (chunk > 0) {
            int blocks = (chunk + threads - 1) / threads;
            quant_b4_chunk<<<blocks, threads, 0, stream>>>(x, (f32x4*)out, chunk);
        }
        int done = chunk << 2;
        int tail = n - done;
        if (tail > 0) {
            int blocks = (tail + threads - 1) / threads;
            quant_b4_tail<<<blocks, threads, 0, stream>>>(x, (f32x4*)out, n, done);
        }
    } else {
        int blocks = (n + threads - 1) / threads;
        if (blocks > 2048) blocks = 2048;
        quant_bits_generic_kernel<<<blocks, threads, 0, stream>>>(x, out, n, B);
    }
}

// Round 7
// 319.132 us; speedup vs baseline: 1.3905x; 1.0049x over previous
//
#include <hip/hip_runtime.h>

// QuantizationLayer: x in [0,1) -> n = round_half_even(x * 2^B - 0.5) in [0, 2^B)
// -> emit B bits MSB-first as float32 (0.0 / 1.0).
//
// B == 4: each input element -> one aligned float4 (16 B) of output.
// Layout (round 6 lesson): keep every instruction lane-contiguous AND keep
// each wave's total footprint contiguous for DRAM page locality.
// Wave w owns elements [w*512, w*512+512): lane l handles e = w*512 + k*64 + l,
// k = 0..8. Loads: 256 B contiguous/instr. Stores: 1 KB contiguous/instr.
// Wave footprint: 2 KB read + 8 KB write, contiguous. ILP = 8.

typedef __attribute__((ext_vector_type(4))) float f32x4;

__global__ __launch_bounds__(256) void quant_b4_wave(
    const float* __restrict__ x, f32x4* __restrict__ out4, int nfull) {
    int tid = blockIdx.x * blockDim.x + threadIdx.x;
    int base = ((tid >> 6) << 9) + (tid & 63);  // wave_id*512 + lane
    if (base >= nfull) return;                  // wave-uniform (nfull % 512 == 0)
    float v[8];
#pragma unroll
    for (int k = 0; k < 8; ++k) v[k] = x[base + k * 64];
#pragma unroll
    for (int k = 0; k < 8; ++k) {
        // x*16 exact (pow2 scale); v_rndne_f32 == np.round (half-to-even);
        // rintf(-0.5) = -0.0 -> (int)0 matches uint8 cast of np.round.
        int n = (int)rintf(v[k] * 16.0f - 0.5f);
        f32x4 o;
        o.x = (float)((n >> 3) & 1);
        o.y = (float)((n >> 2) & 1);
        o.z = (float)((n >> 1) & 1);
        o.w = (float)(n & 1);
        out4[base + k * 64] = o;
    }
}

// Tail (elements [start, n)) — scalar, one float4 store per element
__global__ __launch_bounds__(256) void quant_b4_tail(
    const float* __restrict__ x, f32x4* __restrict__ out4, int n_elems, int start) {
    int i = start + blockIdx.x * blockDim.x + threadIdx.x;
    if (i >= n_elems) return;
    int n = (int)rintf(x[i] * 16.0f - 0.5f);
    f32x4 o;
    o.x = (float)((n >> 3) & 1);
    o.y = (float)((n >> 2) & 1);
    o.z = (float)((n >> 1) & 1);
    o.w = (float)(n & 1);
    out4[i] = o;
}

// Generic fallback for any B (1..8)
__global__ __launch_bounds__(256) void quant_bits_generic_kernel(
    const float* __restrict__ x, float* __restrict__ out, int n_elems, int B) {
    int idx = blockIdx.x * blockDim.x + threadIdx.x;
    int stride = gridDim.x * blockDim.x;
    float step = (float)(1 << B);
    for (int i = idx; i < n_elems; i += stride) {
        float v = x[i];
        int n = (int)rintf(v * step - 0.5f);
        for (int j = 0; j < B; ++j) {
            out[(long long)i * B + j] = (float)((n >> (B - 1 - j)) & 1);
        }
    }
}

extern "C" void kernel_launch(void* const* d_in, const int* in_sizes, int n_in,
                              void* d_out, int out_size, void* d_ws, size_t ws_size,
                              hipStream_t stream) {
    const float* x = (const float*)d_in[0];
    float* out = (float*)d_out;
    int n = in_sizes[0];
    int B = out_size / n;  // bits per element, known on host

    const int threads = 256;

    if (B == 4) {
        int nfull = n & ~511;               // wave-group-covered elements
        if (nfull > 0) {
            int nthreads = nfull >> 3;      // 8 elements per thread
            int blocks = (nthreads + threads - 1) / threads;
            quant_b4_wave<<<blocks, threads, 0, stream>>>(x, (f32x4*)out, nfull);
        }
        int tail = n - nfull;
        if (tail > 0) {
            int blocks = (tail + threads - 1) / threads;
            quant_b4_tail<<<blocks, threads, 0, stream>>>(x, (f32x4*)out, n, nfull);
        }
    } else {
        int blocks = (n + threads - 1) / threads;
        if (blocks > 2048) blocks = 2048;
        quant_bits_generic_kernel<<<blocks, threads, 0, stream>>>(x, out, n, B);
    }
}

// Round 8
// 313.722 us; speedup vs baseline: 1.4145x; 1.0172x over previous
//
#include <hip/hip_runtime.h>

// QuantizationLayer: x in [0,1) -> n = round_half_even(x * 2^B - 0.5) in [0, 2^B)
// -> emit B bits MSB-first as float32 (0.0 / 1.0).
//
// B == 4: each input element -> one aligned float4 (16 B) of output.
// Layout: wave w owns elements [w*512, w*512+512); lane l handles
// e = w*512 + k*64 + l, k=0..7. Loads 256 B/instr, stores 1 KB/instr,
// all lane-contiguous. ILP = 8.
// Round 8 change: NONTEMPORAL stores. Safe now (full-line coverage per
// wave store instr, unlike round 3's 64B-strided-lane NT disaster).
// Rationale: 256 MB output stream == L3 size; cached write-allocate sweeps
// L3 and evicts the input stream. NT keeps the output out of L2/L3.

typedef __attribute__((ext_vector_type(4))) float f32x4;

__global__ __launch_bounds__(256) void quant_b4_wave_nt(
    const float* __restrict__ x, f32x4* __restrict__ out4, int nfull) {
    int tid = blockIdx.x * blockDim.x + threadIdx.x;
    int base = ((tid >> 6) << 9) + (tid & 63);  // wave_id*512 + lane
    if (base >= nfull) return;                  // wave-uniform (nfull % 512 == 0)
    float v[8];
#pragma unroll
    for (int k = 0; k < 8; ++k) v[k] = x[base + k * 64];
#pragma unroll
    for (int k = 0; k < 8; ++k) {
        // x*16 exact (pow2 scale); v_rndne_f32 == np.round (half-to-even);
        // rintf(-0.5) = -0.0 -> (int)0 matches uint8 cast of np.round.
        int n = (int)rintf(v[k] * 16.0f - 0.5f);
        f32x4 o;
        o.x = (float)((n >> 3) & 1);
        o.y = (float)((n >> 2) & 1);
        o.z = (float)((n >> 1) & 1);
        o.w = (float)(n & 1);
        __builtin_nontemporal_store(o, &out4[base + k * 64]);
    }
}

// Tail (elements [start, n)) — scalar, one float4 store per element
__global__ __launch_bounds__(256) void quant_b4_tail(
    const float* __restrict__ x, f32x4* __restrict__ out4, int n_elems, int start) {
    int i = start + blockIdx.x * blockDim.x + threadIdx.x;
    if (i >= n_elems) return;
    int n = (int)rintf(x[i] * 16.0f - 0.5f);
    f32x4 o;
    o.x = (float)((n >> 3) & 1);
    o.y = (float)((n >> 2) & 1);
    o.z = (float)((n >> 1) & 1);
    o.w = (float)(n & 1);
    out4[i] = o;
}

// Generic fallback for any B (1..8)
__global__ __launch_bounds__(256) void quant_bits_generic_kernel(
    const float* __restrict__ x, float* __restrict__ out, int n_elems, int B) {
    int idx = blockIdx.x * blockDim.x + threadIdx.x;
    int stride = gridDim.x * blockDim.x;
    float step = (float)(1 << B);
    for (int i = idx; i < n_elems; i += stride) {
        float v = x[i];
        int n = (int)rintf(v * step - 0.5f);
        for (int j = 0; j < B; ++j) {
            out[(long long)i * B + j] = (float)((n >> (B - 1 - j)) & 1);
        }
    }
}

extern "C" void kernel_launch(void* const* d_in, const int* in_sizes, int n_in,
                              void* d_out, int out_size, void* d_ws, size_t ws_size,
                              hipStream_t stream) {
    const float* x = (const float*)d_in[0];
    float* out = (float*)d_out;
    int n = in_sizes[0];
    int B = out_size / n;  // bits per element, known on host

    const int threads = 256;

    if (B == 4) {
        int nfull = n & ~511;               // wave-group-covered elements
        if (nfull > 0) {
            int nthreads = nfull >> 3;      // 8 elements per thread
            int blocks = (nthreads + threads - 1) / threads;
            quant_b4_wave_nt<<<blocks, threads, 0, stream>>>(x, (f32x4*)out, nfull);
        }
        int tail = n - nfull;
        if (tail > 0) {
            int blocks = (tail + threads - 1) / threads;
            quant_b4_tail<<<blocks, threads, 0, stream>>>(x, (f32x4*)out, n, nfull);
        }
    } else {
        int blocks = (n + threads - 1) / threads;
        if (blocks > 2048) blocks = 2048;
        quant_bits_generic_kernel<<<blocks, threads, 0, stream>>>(x, out, n, B);
    }
}

// Round 9
// 307.345 us; speedup vs baseline: 1.4438x; 1.0208x over previous
//
#include <hip/hip_runtime.h>

// QuantizationLayer: x in [0,1) -> n = round_half_even(x * 2^B - 0.5) in [0, 2^B)
// -> emit B bits MSB-first as float32 (0.0 / 1.0).
//
// B == 4: each input element -> one aligned float4 (16 B) of output.
// Wave-contiguous layout, ILP = 16: wave w owns elements [w*1024, w*1024+1024);
// lane l handles e = w*1024 + k*64 + l, k = 0..15. All 16 loads issued before
// compute (16 outstanding vmem/thread), then compute + NT store per element.
// Loads: 256 B contiguous/instr. Stores: 1 KB contiguous/instr (full-line,
// so NT is safe — round 3's NT disaster was 64B-strided lanes).
// NT stores keep the 256 MB output stream (== L3 size) from sweeping caches.

typedef __attribute__((ext_vector_type(4))) float f32x4;

__global__ __launch_bounds__(256) void quant_b4_wave16(
    const float* __restrict__ x, f32x4* __restrict__ out4, int nfull) {
    int tid = blockIdx.x * blockDim.x + threadIdx.x;
    int base = ((tid >> 6) << 10) + (tid & 63);  // wave_id*1024 + lane
    if (base >= nfull) return;                   // wave-uniform (nfull % 1024 == 0)
    float v[16];
#pragma unroll
    for (int k = 0; k < 16; ++k) v[k] = x[base + k * 64];
#pragma unroll
    for (int k = 0; k < 16; ++k) {
        // x*16 exact (pow2 scale); v_rndne_f32 == np.round (half-to-even);
        // rintf(-0.5) = -0.0 -> (int)0 matches uint8 cast of np.round.
        int n = (int)rintf(v[k] * 16.0f - 0.5f);
        f32x4 o;
        o.x = (float)((n >> 3) & 1);
        o.y = (float)((n >> 2) & 1);
        o.z = (float)((n >> 1) & 1);
        o.w = (float)(n & 1);
        __builtin_nontemporal_store(o, &out4[base + k * 64]);
    }
}

// Tail (elements [start, n)) — scalar, one float4 store per element
__global__ __launch_bounds__(256) void quant_b4_tail(
    const float* __restrict__ x, f32x4* __restrict__ out4, int n_elems, int start) {
    int i = start + blockIdx.x * blockDim.x + threadIdx.x;
    if (i >= n_elems) return;
    int n = (int)rintf(x[i] * 16.0f - 0.5f);
    f32x4 o;
    o.x = (float)((n >> 3) & 1);
    o.y = (float)((n >> 2) & 1);
    o.z = (float)((n >> 1) & 1);
    o.w = (float)(n & 1);
    out4[i] = o;
}

// Generic fallback for any B (1..8)
__global__ __launch_bounds__(256) void quant_bits_generic_kernel(
    const float* __restrict__ x, float* __restrict__ out, int n_elems, int B) {
    int idx = blockIdx.x * blockDim.x + threadIdx.x;
    int stride = gridDim.x * blockDim.x;
    float step = (float)(1 << B);
    for (int i = idx; i < n_elems; i += stride) {
        float v = x[i];
        int n = (int)rintf(v * step - 0.5f);
        for (int j = 0; j < B; ++j) {
            out[(long long)i * B + j] = (float)((n >> (B - 1 - j)) & 1);
        }
    }
}

extern "C" void kernel_launch(void* const* d_in, const int* in_sizes, int n_in,
                              void* d_out, int out_size, void* d_ws, size_t ws_size,
                              hipStream_t stream) {
    const float* x = (const float*)d_in[0];
    float* out = (float*)d_out;
    int n = in_sizes[0];
    int B = out_size / n;  // bits per element, known on host

    const int threads = 256;

    if (B == 4) {
        int nfull = n & ~1023;              // wave-tile-covered elements
        if (nfull > 0) {
            int nthreads = nfull >> 4;      // 16 elements per thread
            int blocks = (nthreads + threads - 1) / threads;
            quant_b4_wave16<<<blocks, threads, 0, stream>>>(x, (f32x4*)out, nfull);
        }
        int tail = n - nfull;
        if (tail > 0) {
            int blocks = (tail + threads - 1) / threads;
            quant_b4_tail<<<blocks, threads, 0, stream>>>(x, (f32x4*)out, n, nfull);
        }
    } else {
        int blocks = (n + threads - 1) / threads;
        if (blocks > 2048) blocks = 2048;
        quant_bits_generic_kernel<<<blocks, threads, 0, stream>>>(x, out, n, B);
    }
}

// Round 10
// 305.745 us; speedup vs baseline: 1.4514x; 1.0052x over previous
//
#include <hip/hip_runtime.h>

// QuantizationLayer: x in [0,1) -> n = round_half_even(x * 2^B - 0.5) in [0, 2^B)
// -> emit B bits MSB-first as float32 (0.0 / 1.0).
//
// B == 4: each input element -> one aligned float4 (16 B) of output.
// Wave-contiguous layout, ILP = 32: wave w owns elements [w*2048, w*2048+2048);
// lane l handles e = w*2048 + k*64 + l, k = 0..31. All 32 loads issued before
// compute (32 outstanding vmem/thread), then compute + NT store per element.
// Loads: 256 B contiguous/instr. Stores: 1 KB contiguous/instr (full-line,
// so NT is safe — round 3's NT disaster was 64B-strided lanes).
// NT stores keep the 256 MB output stream (== L3 size) from sweeping caches;
// input reads stay cached (restore-copy leaves them L3-resident).

typedef __attribute__((ext_vector_type(4))) float f32x4;

__global__ __launch_bounds__(256) void quant_b4_wave32(
    const float* __restrict__ x, f32x4* __restrict__ out4, int nfull) {
    int tid = blockIdx.x * blockDim.x + threadIdx.x;
    int base = ((tid >> 6) << 11) + (tid & 63);  // wave_id*2048 + lane
    if (base >= nfull) return;                   // wave-uniform (nfull % 2048 == 0)
    float v[32];
#pragma unroll
    for (int k = 0; k < 32; ++k) v[k] = x[base + k * 64];
#pragma unroll
    for (int k = 0; k < 32; ++k) {
        // x*16 exact (pow2 scale); v_rndne_f32 == np.round (half-to-even);
        // rintf(-0.5) = -0.0 -> (int)0 matches uint8 cast of np.round.
        int n = (int)rintf(v[k] * 16.0f - 0.5f);
        f32x4 o;
        o.x = (float)((n >> 3) & 1);
        o.y = (float)((n >> 2) & 1);
        o.z = (float)((n >> 1) & 1);
        o.w = (float)(n & 1);
        __builtin_nontemporal_store(o, &out4[base + k * 64]);
    }
}

// Tail (elements [start, n)) — scalar, one float4 store per element
__global__ __launch_bounds__(256) void quant_b4_tail(
    const float* __restrict__ x, f32x4* __restrict__ out4, int n_elems, int start) {
    int i = start + blockIdx.x * blockDim.x + threadIdx.x;
    if (i >= n_elems) return;
    int n = (int)rintf(x[i] * 16.0f - 0.5f);
    f32x4 o;
    o.x = (float)((n >> 3) & 1);
    o.y = (float)((n >> 2) & 1);
    o.z = (float)((n >> 1) & 1);
    o.w = (float)(n & 1);
    out4[i] = o;
}

// Generic fallback for any B (1..8)
__global__ __launch_bounds__(256) void quant_bits_generic_kernel(
    const float* __restrict__ x, float* __restrict__ out, int n_elems, int B) {
    int idx = blockIdx.x * blockDim.x + threadIdx.x;
    int stride = gridDim.x * blockDim.x;
    float step = (float)(1 << B);
    for (int i = idx; i < n_elems; i += stride) {
        float v = x[i];
        int n = (int)rintf(v * step - 0.5f);
        for (int j = 0; j < B; ++j) {
            out[(long long)i * B + j] = (float)((n >> (B - 1 - j)) & 1);
        }
    }
}

extern "C" void kernel_launch(void* const* d_in, const int* in_sizes, int n_in,
                              void* d_out, int out_size, void* d_ws, size_t ws_size,
                              hipStream_t stream) {
    const float* x = (const float*)d_in[0];
    float* out = (float*)d_out;
    int n = in_sizes[0];
    int B = out_size / n;  // bits per element, known on host

    const int threads = 256;

    if (B == 4) {
        int nfull = n & ~2047;              // wave-tile-covered elements
        if (nfull > 0) {
            int nthreads = nfull >> 5;      // 32 elements per thread
            int blocks = (nthreads + threads - 1) / threads;
            quant_b4_wave32<<<blocks, threads, 0, stream>>>(x, (f32x4*)out, nfull);
        }
        int tail = n - nfull;
        if (tail > 0) {
            int blocks = (tail + threads - 1) / threads;
            quant_b4_tail<<<blocks, threads, 0, stream>>>(x, (f32x4*)out, n, nfull);
        }
    } else {
        int blocks = (n + threads - 1) / threads;
        if (blocks > 2048) blocks = 2048;
        quant_bits_generic_kernel<<<blocks, threads, 0, stream>>>(x, out, n, B);
    }
}